// Round 1
// 735.576 us; speedup vs baseline: 1.0102x; 1.0102x over previous
//
#include <hip/hip_runtime.h>
#include <cstdio>

// ---------------------------------------------------------------------------
// GCN 2-layer forward on MI355X.  Round 5: wide-gather aggregation.
// Pipeline:
//   1. k_bhist:     bucket histogram of dst>>8  (LDS-privatized)
//   2. k_bscan:     scan 391 buckets -> bbase[], init gcur[]
//   3. k_partition: edges -> tmp[] packed (src,dst), bucket-partitioned
//   4. k_bucket:    per-bucket LDS sort -> esrc[], off[], dinv[]
//   5. k_castWT:    W -> (Wh,Wl) fp16 split, TRANSPOSED [N][K]
//   6. k_gemm_mfma<float,3>:  h1 = fp16(x @ W1)  via Ah*Bh+Ah*Bl+Al*Bh
//   7. agg1 (wave/node, fp32 acc) + bias + relu -> h1r fp16
//   8. k_gemm_mfma<half,2>:   h2 = fp16(h1r @ W2) via A*Bh+A*Bl
//   9. agg2 + bias -> d_out fp32
// Round-5 change: k_agg restructured so each lane loads 16 B (dwordx4) and a
// single wave-load covers EPL=64*16B/(C*2B) edge rows (2 rows at C=256,
// 4 rows at C=128); 8/16 edges per unrolled iteration; edge-slot partials
// combined with __shfl_xor at the end.  Targets the ~43 cy/edge/CU issue
// bottleneck seen in rocprof (VALUBusy 33%, hbm 48%, occupancy 80%).
// ---------------------------------------------------------------------------

#define NPB 256        // nodes per bucket (power of 2: bucket = dst >> 8)
#define PCHUNK 8192    // edges per partition block

typedef _Float16 half4v __attribute__((ext_vector_type(4)));
typedef _Float16 half8v __attribute__((ext_vector_type(8)));
typedef float    f32x4  __attribute__((ext_vector_type(4)));
typedef float    f32x8  __attribute__((ext_vector_type(8)));

__global__ __launch_bounds__(256) void k_zero(int* p, int n) {
  int i = blockIdx.x * 256 + threadIdx.x;
  if (i < n) p[i] = 0;
}

// 1. bucket histogram, LDS-privatized
__global__ __launch_bounds__(256) void k_bhist(const int* __restrict__ dst,
                                               int* __restrict__ bcnt,
                                               int e, int nb) {
  __shared__ int h[512];
  for (int i = threadIdx.x; i < nb; i += 256) h[i] = 0;
  __syncthreads();
  int c0 = blockIdx.x * PCHUNK;
  int c1 = min(c0 + PCHUNK, e);
  for (int i = c0 + threadIdx.x; i < c1; i += 256)
    atomicAdd(&h[dst[i] >> 8], 1);
  __syncthreads();
  for (int i = threadIdx.x; i < nb; i += 256)
    if (h[i]) atomicAdd(&bcnt[i], h[i]);
}

// 2. single-block scan of bucket counts -> bbase[0..nb], gcur init
__global__ __launch_bounds__(512) void k_bscan(const int* __restrict__ bcnt,
                                               int* __restrict__ bbase,
                                               int* __restrict__ gcur, int nb) {
  __shared__ int sm[512];
  int tid = threadIdx.x;
  sm[tid] = (tid < nb) ? bcnt[tid] : 0;
  __syncthreads();
  for (int d = 1; d < 512; d <<= 1) {
    int t = (tid >= d) ? sm[tid - d] : 0;
    __syncthreads();
    sm[tid] += t;
    __syncthreads();
  }
  int ex = (tid == 0) ? 0 : sm[tid - 1];
  if (tid < nb) {
    bbase[tid] = ex;
    gcur[tid] = ex;
  }
  if (tid == nb) bbase[nb] = sm[nb - 1];
}

// 3. bucket partition: contiguous runs of packed (src,dst) per (block,bucket)
__global__ __launch_bounds__(256) void k_partition(const int* __restrict__ src,
                                                   const int* __restrict__ dst,
                                                   int* __restrict__ gcur,
                                                   uint2* __restrict__ tmp,
                                                   int e, int nb) {
  __shared__ int hist[512];
  __shared__ int base[512];
  for (int i = threadIdx.x; i < nb; i += 256) hist[i] = 0;
  __syncthreads();
  int c0 = blockIdx.x * PCHUNK;
  int c1 = min(c0 + PCHUNK, e);
  for (int i = c0 + threadIdx.x; i < c1; i += 256)
    atomicAdd(&hist[dst[i] >> 8], 1);
  __syncthreads();
  for (int i = threadIdx.x; i < nb; i += 256) {
    int c = hist[i];
    base[i] = c ? atomicAdd(&gcur[i], c) : 0;
    hist[i] = 0;  // reuse as local cursor
  }
  __syncthreads();
  for (int i = c0 + threadIdx.x; i < c1; i += 256) {
    int d = dst[i];
    int b = d >> 8;
    int pos = base[b] + atomicAdd(&hist[b], 1);
    uint2 v;
    v.x = (unsigned)src[i];
    v.y = (unsigned)d;
    tmp[pos] = v;
  }
}

// 4. per-bucket sort: produce esrc (sorted by dst), off[], dinv[]
__global__ __launch_bounds__(256) void k_bucket(const uint2* __restrict__ tmp,
                                                const int* __restrict__ bbase,
                                                int* __restrict__ off,
                                                float* __restrict__ dinv,
                                                int* __restrict__ esrc, int n) {
  __shared__ int lcnt[NPB];
  __shared__ int lsum[NPB];
  __shared__ int lcur[NPB];
  const int b = blockIdx.x;
  const int tid = threadIdx.x;
  const int r0 = b << 8;
  const int nn = min(NPB, n - r0);
  const int lo = bbase[b], hi = bbase[b + 1];

  lcnt[tid] = 0;
  __syncthreads();
  for (int i = lo + tid; i < hi; i += 256)
    atomicAdd(&lcnt[tmp[i].y & (NPB - 1)], 1);
  __syncthreads();
  lsum[tid] = lcnt[tid];
  __syncthreads();
  for (int d = 1; d < NPB; d <<= 1) {
    int t = (tid >= d) ? lsum[tid - d] : 0;
    __syncthreads();
    lsum[tid] += t;
    __syncthreads();
  }
  int ex = (tid == 0) ? 0 : lsum[tid - 1];
  if (tid < nn) {
    off[r0 + tid] = lo + ex;
    dinv[r0 + tid] = rsqrtf((float)(lcnt[tid] + 1));  // +1 self loop
    lcur[tid] = lo + ex;
  }
  if (r0 + nn == n && tid == 0) off[n] = hi;
  __syncthreads();
  for (int i = lo + tid; i < hi; i += 256) {
    uint2 t2 = tmp[i];
    int pos = atomicAdd(&lcur[t2.y & (NPB - 1)], 1);
    esrc[pos] = (int)t2.x;
  }
}

// ---------------------------------------------------------------------------
// 5. W -> split fp16, transposed: WhT/WlT are [N][K] so the GEMM B-fragment
// (8 consecutive k at fixed n) is one contiguous 16 B load.
// ---------------------------------------------------------------------------
__global__ __launch_bounds__(256) void k_castWT(const float* __restrict__ W,
                                                _Float16* __restrict__ WhT,
                                                _Float16* __restrict__ WlT,
                                                int K, int N) {
  int i = blockIdx.x * 256 + threadIdx.x;
  if (i >= K * N) return;
  int n = i % N, k = i / N;      // coalesced read of W[k][n]
  float v = W[i];
  _Float16 h = (_Float16)v;
  WhT[(size_t)n * K + k] = h;
  WlT[(size_t)n * K + k] = (_Float16)(v - (float)h);
}

// ---------------------------------------------------------------------------
// 6/8. MFMA GEMM: C[M,N] = fp16(A[M,K] @ B[K,N]), fp32 accumulate.
// NTERMS=3 (AT=float):    acc += Ah*Bh + Ah*Bl + Al*Bh   (fp32-exact)
// NTERMS=2 (AT=_Float16): acc += A*Bh + A*Bl
// Tile: 128x128, BK=32, 4 waves, each wave 64x64 = 4x4 frags of 16x16x32.
// ---------------------------------------------------------------------------
template <typename AT, int NTERMS>
__global__ __launch_bounds__(256, 2) void k_gemm_mfma(
    const AT* __restrict__ A, const _Float16* __restrict__ BhT,
    const _Float16* __restrict__ BlT, _Float16* __restrict__ C,
    int M, int N, int K) {
  constexpr bool SPLITA = (NTERMS == 3);
  __shared__ _Float16 Ah[128][40];
  __shared__ _Float16 Al[SPLITA ? 128 : 1][40];

  const int tid = threadIdx.x;
  const int bm = blockIdx.x * 128;
  const int bn = blockIdx.y * 128;

  // staging map: thread -> (row, 16-wide k segment)
  const int arow = tid >> 1;
  const int acol = (tid & 1) * 16;
  const bool avalid = (bm + arow) < M;
  const AT* aptr = A + (size_t)(bm + arow) * K + acol;

  // wave decomposition
  const int wave = tid >> 6, lane = tid & 63;
  const int wm = (wave & 1) * 64, wn = (wave >> 1) * 64;
  const int lr = lane & 15, quad = lane >> 4;

  const _Float16* bh0 = BhT + (size_t)(bn + wn + lr) * K + quad * 8;
  const _Float16* bl0 = BlT + (size_t)(bn + wn + lr) * K + quad * 8;

  f32x4 acc[4][4] = {};

  for (int k0 = 0; k0 < K; k0 += 32) {
    __syncthreads();
    if (avalid) {
#pragma unroll
      for (int ii = 0; ii < 4; ++ii) {
        if constexpr (SPLITA) {
          f32x4 v = *(const f32x4*)(aptr + k0 + ii * 4);
          half4v hv, lv;
#pragma unroll
          for (int j = 0; j < 4; ++j) {
            hv[j] = (_Float16)v[j];
            lv[j] = (_Float16)(v[j] - (float)hv[j]);
          }
          *(half4v*)&Ah[arow][acol + ii * 4] = hv;
          *(half4v*)&Al[arow][acol + ii * 4] = lv;
        } else {
          half4v v = *(const half4v*)(aptr + k0 + ii * 4);
          *(half4v*)&Ah[arow][acol + ii * 4] = v;
        }
      }
    } else {
      half4v z = {};
#pragma unroll
      for (int ii = 0; ii < 4; ++ii) {
        *(half4v*)&Ah[arow][acol + ii * 4] = z;
        if constexpr (SPLITA) *(half4v*)&Al[arow][acol + ii * 4] = z;
      }
    }
    __syncthreads();

    half8v af[4], alf[4], bhf[4], blf[4];
#pragma unroll
    for (int mi = 0; mi < 4; ++mi) {
      af[mi] = *(const half8v*)&Ah[wm + mi * 16 + lr][quad * 8];
      if constexpr (SPLITA)
        alf[mi] = *(const half8v*)&Al[wm + mi * 16 + lr][quad * 8];
    }
#pragma unroll
    for (int ni = 0; ni < 4; ++ni) {
      bhf[ni] = *(const half8v*)(bh0 + (size_t)(ni * 16) * K + k0);
      blf[ni] = *(const half8v*)(bl0 + (size_t)(ni * 16) * K + k0);
    }
#pragma unroll
    for (int mi = 0; mi < 4; ++mi)
#pragma unroll
      for (int ni = 0; ni < 4; ++ni) {
        acc[mi][ni] = __builtin_amdgcn_mfma_f32_16x16x32_f16(
            af[mi], bhf[ni], acc[mi][ni], 0, 0, 0);
        acc[mi][ni] = __builtin_amdgcn_mfma_f32_16x16x32_f16(
            af[mi], blf[ni], acc[mi][ni], 0, 0, 0);
        if constexpr (SPLITA)
          acc[mi][ni] = __builtin_amdgcn_mfma_f32_16x16x32_f16(
              alf[mi], bhf[ni], acc[mi][ni], 0, 0, 0);
      }
  }

  // epilogue: C/D frag col=lane&15, row=quad*4+r
#pragma unroll
  for (int mi = 0; mi < 4; ++mi)
#pragma unroll
    for (int r = 0; r < 4; ++r) {
      int row = bm + wm + mi * 16 + quad * 4 + r;
      if (row < M) {
#pragma unroll
        for (int ni = 0; ni < 4; ++ni)
          C[(size_t)row * N + bn + wn + ni * 16 + lr] =
              (_Float16)acc[mi][ni][r];
      }
    }
}

// ---------------------------------------------------------------------------
// Aggregation: one wave per destination node, wide-gather version.
//   LPE = C/8 lanes cover one row (each lane 8 ch = 16 B dwordx4 load)
//   EPL = 64/LPE edge rows gathered per wave-load (2 at C=256, 4 at C=128)
//   U   = 4 unrolled groups -> U*EPL edges in flight per iteration
// Edge-slot partial sums combined with __shfl_xor; lanes of slot 0 write.
// out = di * ( di*h[i] + sum_e dinv[src]*h[src] ) + bias  [; relu]
// ---------------------------------------------------------------------------
template <int C, bool RELU, typename OutT>
__global__ __launch_bounds__(256) void k_agg(const _Float16* __restrict__ h,
                                             const int* __restrict__ esrc,
                                             const int* __restrict__ off,
                                             const float* __restrict__ dinv,
                                             const float* __restrict__ bias,
                                             OutT* __restrict__ out, int n) {
  constexpr int LPE = C / 8;     // lanes per edge row
  constexpr int EPL = 64 / LPE;  // edge rows per wave-load
  constexpr int U = 4;           // unrolled groups
  int gwave = (blockIdx.x * 256 + threadIdx.x) >> 6;
  int lane = threadIdx.x & 63;
  if (gwave >= n) return;
  const int i = gwave;
  const int eslot = lane / LPE;
  const int sub = lane % LPE;
  const float di = dinv[i];
  const _Float16* hb = h + sub * 8;

  f32x8 acc = {};
  if (eslot == 0)
    acc = di * __builtin_convertvector(*(const half8v*)(hb + (size_t)i * C),
                                       f32x8);

  int e = off[i];
  const int e1 = off[i + 1];
  for (; e + U * EPL <= e1; e += U * EPL) {
    int s[U];
#pragma unroll
    for (int g = 0; g < U; ++g) s[g] = esrc[e + g * EPL + eslot];
    float w[U];
    half8v v[U];
#pragma unroll
    for (int g = 0; g < U; ++g) {
      w[g] = dinv[s[g]];
      v[g] = *(const half8v*)(hb + (size_t)s[g] * C);
    }
#pragma unroll
    for (int g = 0; g < U; ++g)
      acc += w[g] * __builtin_convertvector(v[g], f32x8);
  }
  for (; e < e1; e += EPL) {
    int eg = e + eslot;
    if (eg < e1) {
      int s = esrc[eg];
      acc += dinv[s] * __builtin_convertvector(
                           *(const half8v*)(hb + (size_t)s * C), f32x8);
    }
  }

  // combine edge-slot partials (all lanes end up with the total)
#pragma unroll
  for (int j = 0; j < 8; ++j) {
    float t = acc[j];
    if constexpr (EPL >= 4) t += __shfl_xor(t, 16);
    t += __shfl_xor(t, 32);
    acc[j] = t;
  }

  if (eslot == 0) {
    f32x8 bv = *(const f32x8*)(bias + sub * 8);
    f32x8 r = acc * di + bv;
    if (RELU) {
#pragma unroll
      for (int j = 0; j < 8; ++j) r[j] = fmaxf(r[j], 0.f);
    }
    if constexpr (sizeof(OutT) == 2) {
      *(half8v*)(out + (size_t)i * C + sub * 8) =
          __builtin_convertvector(r, half8v);
    } else {
      *(f32x8*)(out + (size_t)i * C + sub * 8) = r;
    }
  }
}

// ---------------------------------------------------------------------------
extern "C" void kernel_launch(void* const* d_in, const int* in_sizes, int n_in,
                              void* d_out, int out_size, void* d_ws, size_t ws_size,
                              hipStream_t stream) {
  const float* x  = (const float*)d_in[0];
  const int*   ei = (const int*)d_in[1];
  const float* W1 = (const float*)d_in[2];
  const float* b1 = (const float*)d_in[3];
  const float* W2 = (const float*)d_in[4];
  const float* b2 = (const float*)d_in[5];
  float* out = (float*)d_out;

  const int IN_CH = 256, HID = 256, OUT = 128;
  const int N = in_sizes[0] / IN_CH;   // 100000
  const int E = in_sizes[1] / 2;       // 3200000
  const int* src = ei;
  const int* dst = ei + E;
  const int NB = (N + NPB - 1) / NPB;  // 391 buckets

  // workspace layout
  char* p = (char*)d_ws;
  auto alloc = [&](size_t bytes) {
    void* r = (void*)p;
    p += (bytes + 255) & ~(size_t)255;
    return r;
  };
  _Float16* h1   = (_Float16*)alloc((size_t)N * HID * 2);  // reused as h2
  _Float16* h1r  = (_Float16*)alloc((size_t)N * HID * 2);
  int*      esrc = (int*)alloc((size_t)E * 4);
  uint2*    tmp  = (uint2*)alloc((size_t)E * 8);
  int*      off  = (int*)alloc((size_t)(N + 1) * 4);
  float*    dinv = (float*)alloc((size_t)N * 4);
  int*      bcnt = (int*)alloc((size_t)(NB + 1) * 4);
  int*      bbase= (int*)alloc((size_t)(NB + 1) * 4);
  int*      gcur = (int*)alloc((size_t)(NB + 1) * 4);
  _Float16* w1h  = (_Float16*)alloc((size_t)IN_CH * HID * 2);
  _Float16* w1l  = (_Float16*)alloc((size_t)IN_CH * HID * 2);
  _Float16* w2h  = (_Float16*)alloc((size_t)HID * OUT * 2);
  _Float16* w2l  = (_Float16*)alloc((size_t)HID * OUT * 2);
  if ((size_t)(p - (char*)d_ws) > ws_size) {
    fprintf(stderr, "kernel_launch: ws too small (need %zu, have %zu)\n",
            (size_t)(p - (char*)d_ws), ws_size);
    return;
  }

  const int nBlkP = (E + PCHUNK - 1) / PCHUNK;  // 391

  // 1-2. bucket histogram + scan
  k_zero<<<(NB + 255) / 256, 256, 0, stream>>>(bcnt, NB);
  k_bhist<<<nBlkP, 256, 0, stream>>>(dst, bcnt, E, NB);
  k_bscan<<<1, 512, 0, stream>>>(bcnt, bbase, gcur, NB);
  // 3. partition into buckets
  k_partition<<<nBlkP, 256, 0, stream>>>(src, dst, gcur, tmp, E, NB);
  // 4. per-bucket sort -> esrc, off, dinv
  k_bucket<<<NB, 256, 0, stream>>>(tmp, bbase, off, dinv, esrc, N);
  // 5. W splits (transposed)
  k_castWT<<<(IN_CH * HID + 255) / 256, 256, 0, stream>>>(W1, w1h, w1l, IN_CH, HID);
  k_castWT<<<(HID * OUT + 255) / 256, 256, 0, stream>>>(W2, w2h, w2l, HID, OUT);
  // 6. h1 = fp16(x @ W1)  (split-fp16 MFMA, 3 terms)
  dim3 g1((N + 127) / 128, HID / 128);
  k_gemm_mfma<float, 3><<<g1, 256, 0, stream>>>(x, w1h, w1l, h1, N, HID, IN_CH);
  // 7. agg layer 1 (+bias, relu) -> h1r fp16
  int aggBlk = (N + 3) / 4;  // 4 waves per block, wave per node
  k_agg<256, true, _Float16><<<aggBlk, 256, 0, stream>>>(h1, esrc, off, dinv, b1, h1r, N);
  // 8. h2 = fp16(h1r @ W2)  (2 terms; writes into h1 buffer)
  dim3 g2((N + 127) / 128, OUT / 128);
  k_gemm_mfma<_Float16, 2><<<g2, 256, 0, stream>>>(h1r, w2h, w2l, h1, N, OUT, HID);
  // 9. agg layer 2 (+bias) -> out fp32
  k_agg<128, false, float><<<aggBlk, 256, 0, stream>>>(h1, esrc, off, dinv, b2, out, N);
}